// Round 1
// baseline (3727.402 us; speedup 1.0000x reference)
//
#include <hip/hip_runtime.h>
#include <cstdint>

#define NPART 32768
#define HALFN 16384

// ws float-offsets
#define WS_W     0
#define WS_M     2048
#define WS_B     4096
#define WS_MEAN  6176
#define WS_H     6240
#define WS_C0    6272
#define WS_LML   6273
#define WS_PMY   6280
#define WS_PZY   6536
#define WS_PMLW  6792
#define WS_PZLW  7048
#define WS_PSE   7304

struct HK { uint32_t a, b; };

// JAX threefry2x32 (20 rounds, 5 key injections)
__host__ __device__ inline HK tf2x32(uint32_t k0, uint32_t k1, uint32_t x0, uint32_t x1) {
  uint32_t kx = k0 ^ k1 ^ 0x1BD11BDAu;
#define TF_R(r) { x0 += x1; x1 = (x1 << (r)) | (x1 >> (32 - (r))); x1 ^= x0; }
  x0 += k0; x1 += k1;
  TF_R(13) TF_R(15) TF_R(26) TF_R(6)
  x0 += k1; x1 += kx + 1u;
  TF_R(17) TF_R(29) TF_R(16) TF_R(24)
  x0 += kx; x1 += k0 + 2u;
  TF_R(13) TF_R(15) TF_R(26) TF_R(6)
  x0 += k0; x1 += k1 + 3u;
  TF_R(17) TF_R(29) TF_R(16) TF_R(24)
  x0 += k1; x1 += kx + 4u;
  TF_R(13) TF_R(15) TF_R(26) TF_R(6)
  x0 += kx; x1 += k0 + 5u;
#undef TF_R
  HK r; r.a = x0; r.b = x1; return r;
}

// XLA ErfInv32 polynomial (Giles)
__device__ inline float erfinv_f(float x) {
  float w = -log1pf(-x * x);
  float p;
  if (w < 5.0f) {
    w -= 2.5f;
    p = 2.81022636e-08f;
    p = fmaf(p, w, 3.43273939e-07f);
    p = fmaf(p, w, -3.5233877e-06f);
    p = fmaf(p, w, -4.39150654e-06f);
    p = fmaf(p, w, 0.00021858087f);
    p = fmaf(p, w, -0.00125372503f);
    p = fmaf(p, w, -0.00417768164f);
    p = fmaf(p, w, 0.246640727f);
    p = fmaf(p, w, 1.50140941f);
  } else {
    w = sqrtf(w) - 3.0f;
    p = -0.000200214257f;
    p = fmaf(p, w, 0.000100950558f);
    p = fmaf(p, w, 0.00134934322f);
    p = fmaf(p, w, -0.00367342844f);
    p = fmaf(p, w, 0.00573950773f);
    p = fmaf(p, w, -0.0076224613f);
    p = fmaf(p, w, 0.00943887047f);
    p = fmaf(p, w, 1.00167406f);
    p = fmaf(p, w, 2.83297682f);
  }
  return p * x;
}

__device__ inline float u01(uint32_t bits) {
  return __uint_as_float((bits >> 9) | 0x3f800000u) - 1.0f;
}

// Precompute: L_R = chol(Rc Rc^T), Linv, W = Linv C, M = W Qc, b[t] = Linv obs_t, C0
__global__ __launch_bounds__(1024) void kp_kernel(float* __restrict__ ws,
    const float* __restrict__ obs, const float* __restrict__ Cm,
    const float* __restrict__ Qc, const float* __restrict__ Rc) {
  __shared__ float Ls[32][32];
  __shared__ float Li[32][32];
  __shared__ float Wsh[32][64];
  const int tid = threadIdx.x;
  const int i = tid >> 5, j = tid & 31;
  // R = Rc Rc^T
  {
    float a = 0.0f;
    for (int k = 0; k < 32; ++k) a = fmaf(Rc[i * 32 + k], Rc[j * 32 + k], a);
    Ls[i][j] = a;
  }
  __syncthreads();
  // Cholesky (lower), right-looking
  for (int k = 0; k < 32; ++k) {
    if (tid == 0) Ls[k][k] = sqrtf(Ls[k][k]);
    __syncthreads();
    if (tid > k && tid < 32) Ls[tid][k] /= Ls[k][k];
    __syncthreads();
    if (i > k && j > k && j <= i) Ls[i][j] = fmaf(-Ls[i][k], Ls[j][k], Ls[i][j]);
    __syncthreads();
  }
  // Linv (forward substitution, one column per thread)
  if (tid < 32) {
    for (int r = 0; r < 32; ++r) Li[r][tid] = 0.0f;
    Li[tid][tid] = 1.0f / Ls[tid][tid];
    for (int r = tid + 1; r < 32; ++r) {
      float s = 0.0f;
      for (int m = tid; m < r; ++m) s = fmaf(Ls[r][m], Li[m][tid], s);
      Li[r][tid] = -s / Ls[r][r];
    }
  }
  __syncthreads();
  if (tid == 0) {
    float ld = 0.0f;
    for (int k = 0; k < 32; ++k) ld += logf(Ls[k][k]);
    ws[WS_C0] = -0.5f * 32.0f * 1.8378770664093453f - ld;
    ws[WS_LML] = 0.0f;
  }
  // W = Linv @ C  [32][64]
  for (int idx = tid; idx < 2048; idx += 1024) {
    int o = idx >> 6, d = idx & 63;
    float a = 0.0f;
    for (int k = 0; k < 32; ++k) a = fmaf(Li[o][k], Cm[k * 64 + d], a);
    Wsh[o][d] = a;
    ws[WS_W + idx] = a;
  }
  __syncthreads();
  // M = W @ Qc  [32][64]
  for (int idx = tid; idx < 2048; idx += 1024) {
    int o = idx >> 6, d = idx & 63;
    float a = 0.0f;
    for (int k = 0; k < 64; ++k) a = fmaf(Wsh[o][k], Qc[k * 64 + d], a);
    ws[WS_M + idx] = a;
  }
  // b[t] = Linv @ obs_t  [65][32]
  for (int idx = tid; idx < 2080; idx += 1024) {
    int t = idx >> 5, o = idx & 31;
    float a = 0.0f;
    for (int k = 0; k < 32; ++k) a = fmaf(Li[o][k], obs[t * 32 + k], a);
    ws[WS_B + idx] = a;
  }
}

// Wide per-step kernel: 2 threads/particle (halves of 64 dims). Generates E (or X0),
// computes lw, gumbel, and block-partial softmax stats + weighted E sums.
// mat_off: WS_W (init: z = b0 - W X) or WS_M (steps: z = h - M E)
// vec_off: WS_B (b0) or WS_H (h)
__global__ __launch_bounds__(256) void kgen_kernel(float* __restrict__ ws,
    uint32_t nk0, uint32_t nk1, uint32_t uk0, uint32_t uk1,
    int mat_off, int vec_off) {
  __shared__ float Ms[2048];
  __shared__ float hC[33];
  __shared__ float sSE[4][64];
  __shared__ float sRed[4][4];
  __shared__ float sBlk[2];
  const int tid = threadIdx.x;
  {
    const float4* src = (const float4*)(ws + mat_off);
    float4* dst = (float4*)Ms;
    dst[tid] = src[tid];
    dst[tid + 256] = src[tid + 256];
    if (tid < 32) hC[tid] = ws[vec_off + tid];
    if (tid == 32) hC[32] = ws[WS_C0];
  }
  __syncthreads();

  const int half = tid & 1;
  const int n = blockIdx.x * 128 + (tid >> 1);
  const int d0 = half << 5;
  const uint32_t fbase = (uint32_t)(((n < HALFN) ? n : (n - HALFN)) * 64 + d0);
  const bool hi = (n >= HALFN);

  float E[32];
#pragma unroll
  for (int j = 0; j < 32; ++j) {
    HK o = tf2x32(nk0, nk1, fbase + (uint32_t)j, fbase + (uint32_t)j + 1048576u);
    uint32_t bits = hi ? o.b : o.a;
    float f = u01(bits);
    float u = fmaxf(-0.99999994f, fmaf(f, 2.0f, -0.99999994f));
    E[j] = 1.41421354f * erfinv_f(u);
  }

  // z = hC - Mat * E (each thread does its 32-dim half; combine via shfl)
  float s2 = 0.0f;
  for (int o = 0; o < 32; ++o) {
    const float4* mr = (const float4*)(Ms + o * 64 + d0);
    float acc = 0.0f;
#pragma unroll
    for (int q = 0; q < 8; ++q) {
      float4 m4 = mr[q];
      acc = fmaf(m4.x, E[4 * q + 0], acc);
      acc = fmaf(m4.y, E[4 * q + 1], acc);
      acc = fmaf(m4.z, E[4 * q + 2], acc);
      acc = fmaf(m4.w, E[4 * q + 3], acc);
    }
    float accp = __shfl_xor(acc, 1, 64);
    float z = hC[o] - acc - accp;
    s2 = fmaf(z, z, s2);
  }
  const float lw = hC[32] - 0.5f * s2;

  // gumbel from uniform key (both half-threads compute identically)
  const uint32_t mm_ = (uint32_t)(n & (HALFN - 1));
  HK og = tf2x32(uk0, uk1, mm_, mm_ + (uint32_t)HALFN);
  float uf = u01(hi ? og.b : og.a);
  float gum = -logf(-logf(uf + 1e-10f) + 1e-10f);
  const float y = (lw + gum) * 2.0f;  // 1/TEMPERATURE = 2

  // wave maxes (duplicates across the 2 half-lanes are harmless)
  float my = y, mlw = lw;
#pragma unroll
  for (int mk = 1; mk < 64; mk <<= 1) {
    my = fmaxf(my, __shfl_xor(my, mk, 64));
    mlw = fmaxf(mlw, __shfl_xor(mlw, mk, 64));
  }
  const int wid = tid >> 6, lane = tid & 63;
  if (lane == 0) { sRed[wid][0] = my; sRed[wid][1] = mlw; }
  __syncthreads();
  if (tid == 0) {
    sBlk[0] = fmaxf(fmaxf(sRed[0][0], sRed[1][0]), fmaxf(sRed[2][0], sRed[3][0]));
    sBlk[1] = fmaxf(fmaxf(sRed[0][1], sRed[1][1]), fmaxf(sRed[2][1], sRed[3][1]));
  }
  __syncthreads();
  const float myb = sBlk[0], mlwb = sBlk[1];
  const float w = expf(y - myb);
  const float wl = expf(lw - mlwb);
  float zy = half ? 0.0f : w;   // count each particle once
  float zl = half ? 0.0f : wl;
#pragma unroll
  for (int mk = 1; mk < 64; mk <<= 1) {
    zy += __shfl_xor(zy, mk, 64);
    zl += __shfl_xor(zl, mk, 64);
  }
  if (lane == 0) { sRed[wid][2] = zy; sRed[wid][3] = zl; }

  // weighted E sums: reduce across particles keeping halves separate (skip bit0)
  float v[32];
#pragma unroll
  for (int j = 0; j < 32; ++j) v[j] = w * E[j];
#pragma unroll
  for (int mk = 2; mk < 64; mk <<= 1) {
#pragma unroll
    for (int j = 0; j < 32; ++j) v[j] += __shfl_xor(v[j], mk, 64);
  }
  if (lane < 2) {
#pragma unroll
    for (int j = 0; j < 32; ++j) sSE[wid][lane * 32 + j] = v[j];
  }
  __syncthreads();
  if (tid < 64) {
    ws[WS_PSE + blockIdx.x * 64 + tid] =
        sSE[0][tid] + sSE[1][tid] + sSE[2][tid] + sSE[3][tid];
  }
  if (tid == 0) {
    ws[WS_PMY + blockIdx.x] = myb;
    ws[WS_PZY + blockIdx.x] = sRed[0][2] + sRed[1][2] + sRed[2][2] + sRed[3][2];
    ws[WS_PMLW + blockIdx.x] = mlwb;
    ws[WS_PZLW + blockIdx.x] = sRed[0][3] + sRed[1][3] + sRed[2][3] + sRed[3][3];
  }
}

// Single-block combine: softmax partials -> r -> quad -> mean, h; lml accumulation.
__global__ __launch_bounds__(1024) void kb_kernel(float* __restrict__ ws,
    const float* __restrict__ Am, const float* __restrict__ Qc,
    const float* __restrict__ Qt, float* __restrict__ dout, int s) {
  const bool first = (s == 0);
  const bool fin = (s == 64);
  __shared__ float red[256], red2[256];
  __shared__ float eb[256];
  __shared__ float se16[16][64];
  __shared__ float q16[64][16];
  __shared__ float rv[64], mn[64], uarr[64];
  __shared__ float scal[4];
  const int tid = threadIdx.x;

  if (tid < 256) { red[tid] = ws[WS_PMY + tid]; red2[tid] = ws[WS_PMLW + tid]; }
  __syncthreads();
  for (int st = 128; st > 0; st >>= 1) {
    if (tid < st) {
      red[tid] = fmaxf(red[tid], red[tid + st]);
      red2[tid] = fmaxf(red2[tid], red2[tid + st]);
    }
    __syncthreads();
  }
  if (tid == 0) { scal[0] = red[0]; scal[1] = red2[0]; }
  __syncthreads();
  const float myg = scal[0], mlwg = scal[1];
  if (tid < 256) {
    float e = expf(ws[WS_PMY + tid] - myg);
    eb[tid] = e;
    red[tid] = e * ws[WS_PZY + tid];
    red2[tid] = expf(ws[WS_PMLW + tid] - mlwg) * ws[WS_PZLW + tid];
  }
  __syncthreads();
  for (int st = 128; st > 0; st >>= 1) {
    if (tid < st) { red[tid] += red[tid + st]; red2[tid] += red2[tid + st]; }
    __syncthreads();
  }
  if (tid == 0) {
    scal[2] = red[0];  // Z_y
    float lml = ws[WS_LML];
    if (!first) lml += mlwg + logf(red2[0]);
    ws[WS_LML] = lml;
    if (fin) dout[0] = lml;
  }
  __syncthreads();
  if (fin) return;
  const float Zy = scal[2];

  // SE combine (256 blocks x 64 dims)
  {
    int d = tid & 63, c = tid >> 6;
    float p = 0.0f;
    for (int b8 = 0; b8 < 16; ++b8) {
      int b = c * 16 + b8;
      p = fmaf(eb[b], ws[WS_PSE + b * 64 + d], p);
    }
    se16[c][d] = p;
  }
  __syncthreads();
  if (tid < 64) {
    float sg = 0.0f;
    for (int c = 0; c < 16; ++c) sg += se16[c][tid];
    uarr[tid] = sg / Zy;
  }
  __syncthreads();
  if (tid < 64) {
    float r;
    if (first) r = uarr[tid];  // r = weighted mean of X0 directly
    else {
      r = ws[WS_MEAN + tid];
      for (int k = 0; k < 64; ++k) r = fmaf(uarr[k], Qc[tid * 64 + k], r);
    }
    rv[tid] = r;
  }
  __syncthreads();
  // quad_i = r^T Q_i r
  {
    int i = tid >> 4, sl = tid & 15;
    float acc = 0.0f;
    for (int jj = 0; jj < 4; ++jj) {
      int j = sl * 4 + jj;
      const float4* qr = (const float4*)(Qt + (size_t)(i * 64 + j) * 64);
      float inn = 0.0f;
#pragma unroll
      for (int q = 0; q < 16; ++q) {
        float4 v = qr[q];
        inn = fmaf(v.x, rv[4 * q + 0], inn);
        inn = fmaf(v.y, rv[4 * q + 1], inn);
        inn = fmaf(v.z, rv[4 * q + 2], inn);
        inn = fmaf(v.w, rv[4 * q + 3], inn);
      }
      acc = fmaf(rv[j], inn, acc);
    }
    q16[i][sl] = acc;
  }
  __syncthreads();
  if (tid < 64) {
    float qd = 0.0f;
    for (int c = 0; c < 16; ++c) qd += q16[tid][c];
    float ar = 0.0f;
    for (int k = 0; k < 64; ++k) ar = fmaf(Am[tid * 64 + k], rv[k], ar);
    float m2 = rv[tid] + 0.0099f * (ar + qd);  // DT*DAMPING
    mn[tid] = m2;
    ws[WS_MEAN + tid] = m2;
  }
  __syncthreads();
  if (tid < 32) {
    float hv = ws[WS_B + (s + 1) * 32 + tid];
    for (int d = 0; d < 64; ++d) hv = fmaf(-ws[WS_W + tid * 64 + d], mn[d], hv);
    ws[WS_H + tid] = hv;
  }
}

extern "C" void kernel_launch(void* const* d_in, const int* in_sizes, int n_in,
                              void* d_out, int out_size, void* d_ws, size_t ws_size,
                              hipStream_t stream) {
  const float* obs = (const float*)d_in[0];
  const float* Am = (const float*)d_in[1];
  const float* Cm = (const float*)d_in[2];
  const float* Qt = (const float*)d_in[3];
  const float* Qc = (const float*)d_in[4];
  const float* Rc = (const float*)d_in[5];
  float* ws = (float*)d_ws;
  float* out = (float*)d_out;
  (void)in_sizes; (void)n_in; (void)out_size; (void)ws_size;

  // Host-side key chain: root = [0,42]; split -> (k_init, k_scan);
  // per step t: k = fold_in(k_scan, t) = tf(k_scan, 0, t); split(k) -> (k1_uniform, k2_normal)
  HK p0 = tf2x32(0u, 42u, 0u, 2u);
  HK p1 = tf2x32(0u, 42u, 1u, 3u);
  const uint32_t ki0 = p0.a, ki1 = p1.a;  // k_init
  const uint32_t ks0 = p0.b, ks1 = p1.b;  // k_scan

  uint32_t uk[65][2], nk[64][2];
  for (int t = 0; t <= 64; ++t) {
    HK f = tf2x32(ks0, ks1, 0u, (uint32_t)t);
    HK q0 = tf2x32(f.a, f.b, 0u, 2u);
    HK q1 = tf2x32(f.a, f.b, 1u, 3u);
    uk[t][0] = q0.a; uk[t][1] = q1.a;
    if (t < 64) { nk[t][0] = q0.b; nk[t][1] = q1.b; }
  }

  kp_kernel<<<dim3(1), dim3(1024), 0, stream>>>(ws, obs, Cm, Qc, Rc);
  // init: X0 ~ N(0,1) with k_init; z = b0 - W X0; gumbel_0 with uk[0]
  kgen_kernel<<<dim3(256), dim3(256), 0, stream>>>(ws, ki0, ki1, uk[0][0], uk[0][1], WS_W, WS_B);
  for (int s = 0; s < 64; ++s) {
    kb_kernel<<<dim3(1), dim3(1024), 0, stream>>>(ws, Am, Qc, Qt, out, s);
    kgen_kernel<<<dim3(256), dim3(256), 0, stream>>>(ws, nk[s][0], nk[s][1], uk[s + 1][0], uk[s + 1][1], WS_M, WS_H);
  }
  kb_kernel<<<dim3(1), dim3(1024), 0, stream>>>(ws, Am, Qc, Qt, out, 64);
}

// Round 2
// 2612.312 us; speedup vs baseline: 1.4269x; 1.4269x over previous
//
#include <hip/hip_runtime.h>
#include <cstdint>

#define NPART 32768
#define HALFN 16384

// ws float-offsets
#define WS_W     0        // [32][64]
#define WS_M     2048     // [32][64]
#define WS_B     4096     // [65][32]
#define WS_C0    6176
#define WS_PMY   6208     // [256]
#define WS_PZY   6464
#define WS_PMLW  6720
#define WS_PZLW  6976
#define WS_PSE   7232     // [256][64]
#define WS_QP    23616    // [256]
#define WS_CNT   23872    // uint32 barrier counter (zeroed by kp each launch)
#define WS_KI    23880    // 2 uints
#define WS_NK    23884    // 128 uints
#define WS_UK    24012    // 130 uints

struct HK { uint32_t a, b; };

// JAX threefry2x32 (20 rounds, 5 key injections)
__host__ __device__ inline HK tf2x32(uint32_t k0, uint32_t k1, uint32_t x0, uint32_t x1) {
  uint32_t kx = k0 ^ k1 ^ 0x1BD11BDAu;
#define TF_R(r) { x0 += x1; x1 = (x1 << (r)) | (x1 >> (32 - (r))); x1 ^= x0; }
  x0 += k0; x1 += k1;
  TF_R(13) TF_R(15) TF_R(26) TF_R(6)
  x0 += k1; x1 += kx + 1u;
  TF_R(17) TF_R(29) TF_R(16) TF_R(24)
  x0 += kx; x1 += k0 + 2u;
  TF_R(13) TF_R(15) TF_R(26) TF_R(6)
  x0 += k0; x1 += k1 + 3u;
  TF_R(17) TF_R(29) TF_R(16) TF_R(24)
  x0 += k1; x1 += kx + 4u;
  TF_R(13) TF_R(15) TF_R(26) TF_R(6)
  x0 += kx; x1 += k0 + 5u;
#undef TF_R
  HK r; r.a = x0; r.b = x1; return r;
}

// XLA ErfInv32 polynomial
__device__ inline float erfinv_f(float x) {
  float w = -log1pf(-x * x);
  float p;
  if (w < 5.0f) {
    w -= 2.5f;
    p = 2.81022636e-08f;
    p = fmaf(p, w, 3.43273939e-07f);
    p = fmaf(p, w, -3.5233877e-06f);
    p = fmaf(p, w, -4.39150654e-06f);
    p = fmaf(p, w, 0.00021858087f);
    p = fmaf(p, w, -0.00125372503f);
    p = fmaf(p, w, -0.00417768164f);
    p = fmaf(p, w, 0.246640727f);
    p = fmaf(p, w, 1.50140941f);
  } else {
    w = sqrtf(w) - 3.0f;
    p = -0.000200214257f;
    p = fmaf(p, w, 0.000100950558f);
    p = fmaf(p, w, 0.00134934322f);
    p = fmaf(p, w, -0.00367342844f);
    p = fmaf(p, w, 0.00573950773f);
    p = fmaf(p, w, -0.0076224613f);
    p = fmaf(p, w, 0.00943887047f);
    p = fmaf(p, w, 1.00167406f);
    p = fmaf(p, w, 2.83297682f);
  }
  return p * x;
}

__device__ inline float u01(uint32_t bits) {
  return __uint_as_float((bits >> 9) | 0x3f800000u) - 1.0f;
}

// Precompute: chol(R), Linv, W = Linv C, M = W Qc, b[t] = Linv obs_t, C0, keys, cnt=0
__global__ __launch_bounds__(1024) void kp_kernel(float* __restrict__ ws,
    const float* __restrict__ obs, const float* __restrict__ Cm,
    const float* __restrict__ Qc, const float* __restrict__ Rc) {
  __shared__ float Ls[32][32];
  __shared__ float Li[32][32];
  __shared__ float Wsh[32][64];
  const int tid = threadIdx.x;
  const int i = tid >> 5, j = tid & 31;
  uint32_t* wsu = (uint32_t*)ws;
  // keys (parallel over t)
  if (tid <= 64) {
    HK p0 = tf2x32(0u, 42u, 0u, 2u);
    HK p1 = tf2x32(0u, 42u, 1u, 3u);
    uint32_t ks0 = p0.b, ks1 = p1.b;
    HK f = tf2x32(ks0, ks1, 0u, (uint32_t)tid);
    HK q0 = tf2x32(f.a, f.b, 0u, 2u);
    HK q1 = tf2x32(f.a, f.b, 1u, 3u);
    wsu[WS_UK + 2 * tid] = q0.a; wsu[WS_UK + 2 * tid + 1] = q1.a;
    if (tid < 64) { wsu[WS_NK + 2 * tid] = q0.b; wsu[WS_NK + 2 * tid + 1] = q1.b; }
    if (tid == 0) { wsu[WS_KI] = p0.a; wsu[WS_KI + 1] = p1.a; wsu[WS_CNT] = 0u; }
  }
  // R = Rc Rc^T
  {
    float a = 0.0f;
    for (int k = 0; k < 32; ++k) a = fmaf(Rc[i * 32 + k], Rc[j * 32 + k], a);
    Ls[i][j] = a;
  }
  __syncthreads();
  for (int k = 0; k < 32; ++k) {
    if (tid == 0) Ls[k][k] = sqrtf(Ls[k][k]);
    __syncthreads();
    if (tid > k && tid < 32) Ls[tid][k] /= Ls[k][k];
    __syncthreads();
    if (i > k && j > k && j <= i) Ls[i][j] = fmaf(-Ls[i][k], Ls[j][k], Ls[i][j]);
    __syncthreads();
  }
  if (tid < 32) {
    for (int r = 0; r < 32; ++r) Li[r][tid] = 0.0f;
    Li[tid][tid] = 1.0f / Ls[tid][tid];
    for (int r = tid + 1; r < 32; ++r) {
      float s = 0.0f;
      for (int m = tid; m < r; ++m) s = fmaf(Ls[r][m], Li[m][tid], s);
      Li[r][tid] = -s / Ls[r][r];
    }
  }
  __syncthreads();
  if (tid == 0) {
    float ld = 0.0f;
    for (int k = 0; k < 32; ++k) ld += logf(Ls[k][k]);
    ws[WS_C0] = -0.5f * 32.0f * 1.8378770664093453f - ld;
  }
  for (int idx = tid; idx < 2048; idx += 1024) {
    int o = idx >> 6, d = idx & 63;
    float a = 0.0f;
    for (int k = 0; k < 32; ++k) a = fmaf(Li[o][k], Cm[k * 64 + d], a);
    Wsh[o][d] = a;
    ws[WS_W + idx] = a;
  }
  __syncthreads();
  for (int idx = tid; idx < 2048; idx += 1024) {
    int o = idx >> 6, d = idx & 63;
    float a = 0.0f;
    for (int k = 0; k < 64; ++k) a = fmaf(Wsh[o][k], Qc[k * 64 + d], a);
    ws[WS_M + idx] = a;
  }
  for (int idx = tid; idx < 2080; idx += 1024) {
    int t = idx >> 5, o = idx & 31;
    float a = 0.0f;
    for (int k = 0; k < 32; ++k) a = fmaf(Li[o][k], obs[t * 32 + k], a);
    ws[WS_B + idx] = a;
  }
}

// Persistent cooperative kernel: 256 blocks x 512 threads.
// 8 threads per particle-pair (lo=p, hi=p+16384), 8 dims each.
__global__ __launch_bounds__(512, 2) void kmain_kernel(
    float* __restrict__ ws, const float* __restrict__ Am,
    const float* __restrict__ Qcg, const float* __restrict__ Qt,
    float* __restrict__ dout) {
  __shared__ __align__(16) float Ms[2048];
  __shared__ __align__(16) float Wm[2048];
  __shared__ __align__(16) float As[4096];
  __shared__ __align__(16) float Qcs[4096];
  __shared__ __align__(16) float Qs[1024];
  __shared__ float hC[32];
  __shared__ float rS[64], uS[64], mnS[64];
  __shared__ float ebL[256];
  __shared__ float redA[256], redB[256];
  __shared__ float SEw[8][64];
  __shared__ float wred[8][4];
  __shared__ float sc[8];
  __shared__ uint32_t keyL[260];  // [0..127] nk, [128..257] uk, [258..259] ki

  const int tid = threadIdx.x;
  const int bid = blockIdx.x;
  uint32_t* wsu = (uint32_t*)ws;
  uint32_t* cnt = wsu + WS_CNT;

  // prologue loads
  for (int i = tid; i < 2048; i += 512) { Ms[i] = ws[WS_M + i]; Wm[i] = ws[WS_W + i]; }
  for (int i = tid; i < 4096; i += 512) { As[i] = Am[i]; Qcs[i] = Qcg[i]; }
  {
    const int i0 = (bid >> 2) * 4096 + (bid & 3) * 1024;
    for (int i = tid; i < 1024; i += 512) Qs[i] = Qt[i0 + i];
  }
  for (int i = tid; i < 128; i += 512) keyL[i] = wsu[WS_NK + i];
  for (int i = tid; i < 130; i += 512) keyL[128 + i] = wsu[WS_UK + i];
  if (tid == 0) { keyL[258] = wsu[WS_KI]; keyL[259] = wsu[WS_KI + 1]; sc[4] = 0.0f; }
  if (tid < 32) hC[tid] = ws[WS_B + tid];
  const float C0 = ws[WS_C0];
  __syncthreads();

  const int pr = tid >> 3;          // pair within block
  const int l8 = tid & 7;
  const int p = bid * 64 + pr;      // global pair (= lo particle)
  const int d0 = l8 * 8;
  const int wv = tid >> 6, ln = tid & 63;

  float Elo[8], Ehi[8], gl, gh;
  uint32_t tgt = 0;

  auto bar_arrive = [&]() {
    __syncthreads();
    if (tid == 0) {
      __threadfence();
      __hip_atomic_fetch_add(cnt, 1u, __ATOMIC_RELEASE, __HIP_MEMORY_SCOPE_AGENT);
    }
    tgt += 256u;
  };
  auto bar_wait = [&]() {
    if (tid == 0) {
      while (__hip_atomic_load(cnt, __ATOMIC_RELAXED, __HIP_MEMORY_SCOPE_AGENT) < tgt)
        __builtin_amdgcn_s_sleep(1);
      __threadfence();
    }
    __syncthreads();
  };

  auto genE = [&](uint32_t k0, uint32_t k1) {
    const uint32_t fb = (uint32_t)(p * 64 + d0);
#pragma unroll
    for (int j = 0; j < 8; ++j) {
      HK o = tf2x32(k0, k1, fb + (uint32_t)j, fb + (uint32_t)j + 1048576u);
      float fl = u01(o.a), fh = u01(o.b);
      float ul = fmaxf(-0.99999994f, fmaf(fl, 2.0f, -0.99999994f));
      float uh = fmaxf(-0.99999994f, fmaf(fh, 2.0f, -0.99999994f));
      Elo[j] = 1.41421354f * erfinv_f(ul);
      Ehi[j] = 1.41421354f * erfinv_f(uh);
    }
  };
  auto genG = [&](uint32_t k0, uint32_t k1) {
    HK og = tf2x32(k0, k1, (uint32_t)p, (uint32_t)(p + 16384));
    gl = -logf(-logf(u01(og.a) + 1e-10f) + 1e-10f);
    gh = -logf(-logf(u01(og.b) + 1e-10f) + 1e-10f);
  };

  // z = hC - mat*E via ring reduce-scatter over the 8 lanes of a pair; then
  // lw, y, block softmax partials + weighted-E partial sums -> ws.
  auto genTail = [&](const float* matL) {
    float aL[4] = {0.f, 0.f, 0.f, 0.f}, aH[4] = {0.f, 0.f, 0.f, 0.f};
#pragma unroll
    for (int k = 0; k < 8; ++k) {
      if (k) {
#pragma unroll
        for (int q = 0; q < 4; ++q) {
          aL[q] = __shfl(aL[q], (l8 + 1) & 7, 8);
          aH[q] = __shfl(aH[q], (l8 + 1) & 7, 8);
        }
      }
      const int ow = ((l8 + k) & 7) * 4;
#pragma unroll
      for (int q = 0; q < 4; ++q) {
        const float* mr = matL + (ow + q) * 64 + d0;
        float4 m0 = *(const float4*)mr;
        float4 m1 = *(const float4*)(mr + 4);
        float t0 = aL[q];
        t0 = fmaf(m0.x, Elo[0], t0); t0 = fmaf(m0.y, Elo[1], t0);
        t0 = fmaf(m0.z, Elo[2], t0); t0 = fmaf(m0.w, Elo[3], t0);
        t0 = fmaf(m1.x, Elo[4], t0); t0 = fmaf(m1.y, Elo[5], t0);
        t0 = fmaf(m1.z, Elo[6], t0); t0 = fmaf(m1.w, Elo[7], t0);
        aL[q] = t0;
        float t1 = aH[q];
        t1 = fmaf(m0.x, Ehi[0], t1); t1 = fmaf(m0.y, Ehi[1], t1);
        t1 = fmaf(m0.z, Ehi[2], t1); t1 = fmaf(m0.w, Ehi[3], t1);
        t1 = fmaf(m1.x, Ehi[4], t1); t1 = fmaf(m1.y, Ehi[5], t1);
        t1 = fmaf(m1.z, Ehi[6], t1); t1 = fmaf(m1.w, Ehi[7], t1);
        aH[q] = t1;
      }
    }
    const int ob = ((l8 + 7) & 7) * 4;
    float s2l = 0.f, s2h = 0.f;
#pragma unroll
    for (int q = 0; q < 4; ++q) {
      float zl = hC[ob + q] - aL[q], zh = hC[ob + q] - aH[q];
      s2l = fmaf(zl, zl, s2l); s2h = fmaf(zh, zh, s2h);
    }
#pragma unroll
    for (int m = 1; m < 8; m <<= 1) { s2l += __shfl_xor(s2l, m, 8); s2h += __shfl_xor(s2h, m, 8); }
    const float lwL = C0 - 0.5f * s2l, lwH = C0 - 0.5f * s2h;
    const float yl = (lwL + gl) * 2.0f, yh = (lwH + gh) * 2.0f;
    float mv = fmaxf(yl, yh), ml = fmaxf(lwL, lwH);
#pragma unroll
    for (int m = 1; m < 64; m <<= 1) {
      mv = fmaxf(mv, __shfl_xor(mv, m, 64));
      ml = fmaxf(ml, __shfl_xor(ml, m, 64));
    }
    if (ln == 0) { wred[wv][0] = mv; wred[wv][1] = ml; }
    __syncthreads();
    if (tid == 0) {
      float a = wred[0][0], b = wred[0][1];
      for (int q = 1; q < 8; ++q) { a = fmaxf(a, wred[q][0]); b = fmaxf(b, wred[q][1]); }
      sc[0] = a; sc[1] = b;
    }
    __syncthreads();
    const float myb = sc[0], mlb = sc[1];
    const float wLo = expf(yl - myb), wHi = expf(yh - myb);
    float vzy = (l8 == 0) ? (wLo + wHi) : 0.0f;
    float vzl = (l8 == 0) ? (expf(lwL - mlb) + expf(lwH - mlb)) : 0.0f;
#pragma unroll
    for (int m = 1; m < 64; m <<= 1) { vzy += __shfl_xor(vzy, m, 64); vzl += __shfl_xor(vzl, m, 64); }
    if (ln == 0) { wred[wv][2] = vzy; wred[wv][3] = vzl; }
    float v[8];
#pragma unroll
    for (int j = 0; j < 8; ++j) v[j] = fmaf(wHi, Ehi[j], wLo * Elo[j]);
#pragma unroll
    for (int m = 8; m < 64; m <<= 1) {
#pragma unroll
      for (int j = 0; j < 8; ++j) v[j] += __shfl_xor(v[j], m, 64);
    }
    if (ln < 8) {
#pragma unroll
      for (int j = 0; j < 8; ++j) SEw[wv][ln * 8 + j] = v[j];
    }
    __syncthreads();
    if (tid < 64) {
      float ssum = SEw[0][tid];
      for (int q = 1; q < 8; ++q) ssum += SEw[q][tid];
      ws[WS_PSE + (bid << 6) + tid] = ssum;
    }
    if (tid == 0) {
      ws[WS_PMY + bid] = myb; ws[WS_PMLW + bid] = mlb;
      float zy = wred[0][2], zl2 = wred[0][3];
      for (int q = 1; q < 8; ++q) { zy += wred[q][2]; zl2 += wred[q][3]; }
      ws[WS_PZY + bid] = zy; ws[WS_PZLW + bid] = zl2;
    }
  };

  // redundant-per-block combine of step-s partials -> u, r, lml; + quad partial
  auto combine = [&](int s) {
    if (tid < 256) { redA[tid] = ws[WS_PMY + tid]; redB[tid] = ws[WS_PMLW + tid]; }
    __syncthreads();
    for (int st = 128; st > 0; st >>= 1) {
      if (tid < st) {
        redA[tid] = fmaxf(redA[tid], redA[tid + st]);
        redB[tid] = fmaxf(redB[tid], redB[tid + st]);
      }
      __syncthreads();
    }
    const float myg = redA[0], mlwg = redB[0];
    __syncthreads();
    if (tid < 256) {
      float e = expf(ws[WS_PMY + tid] - myg);
      ebL[tid] = e;
      redA[tid] = e * ws[WS_PZY + tid];
      redB[tid] = expf(ws[WS_PMLW + tid] - mlwg) * ws[WS_PZLW + tid];
    }
    __syncthreads();
    for (int st = 128; st > 0; st >>= 1) {
      if (tid < st) { redA[tid] += redA[tid + st]; redB[tid] += redB[tid + st]; }
      __syncthreads();
    }
    if (tid == 0) {
      sc[2] = redA[0];
      if (s > 0) sc[4] += mlwg + logf(redB[0]);
    }
    __syncthreads();
    const float Zy = sc[2];
    {
      const int d = tid & 63, c = tid >> 6;
      const float* pse = ws + WS_PSE + d;
      float pp = 0.0f;
      for (int b8 = 0; b8 < 32; ++b8) {
        int b = c * 32 + b8;
        pp = fmaf(ebL[b], pse[b << 6], pp);
      }
      SEw[c][d] = pp;
    }
    __syncthreads();
    if (tid < 64) {
      float sg = SEw[0][tid];
      for (int c = 1; c < 8; ++c) sg += SEw[c][tid];
      uS[tid] = sg / Zy;
    }
    __syncthreads();
    if (tid < 64) {
      float r;
      if (s == 0) r = uS[tid];
      else {
        r = mnS[tid];
        const float* qr = Qcs + tid * 64;
        for (int k2 = 0; k2 < 64; ++k2) r = fmaf(uS[k2], qr[k2], r);
      }
      rS[tid] = r;
    }
    __syncthreads();
    if (tid < 256) {
      const int jl = tid >> 4, kc = tid & 15;
      const float* qr = Qs + jl * 64 + kc * 4;
      float t0 = qr[0] * rS[kc * 4];
      t0 = fmaf(qr[1], rS[kc * 4 + 1], t0);
      t0 = fmaf(qr[2], rS[kc * 4 + 2], t0);
      t0 = fmaf(qr[3], rS[kc * 4 + 3], t0);
      redA[tid] = t0 * rS[(bid & 3) * 16 + jl];
    }
    __syncthreads();
    for (int st = 128; st > 0; st >>= 1) {
      if (tid < st) redA[tid] += redA[tid + st];
      __syncthreads();
    }
    if (tid == 0) ws[WS_QP + bid] = redA[0];
  };

  auto meanH = [&](int s) {
    if (tid < 64) {
      float qd = ws[WS_QP + tid * 4] + ws[WS_QP + tid * 4 + 1] +
                 ws[WS_QP + tid * 4 + 2] + ws[WS_QP + tid * 4 + 3];
      float ar = 0.0f;
      const float* arow = As + tid * 64;
      for (int k2 = 0; k2 < 64; ++k2) ar = fmaf(arow[k2], rS[k2], ar);
      float m2 = rS[tid] + 0.0099f * (ar + qd);
      mnS[tid] = m2;
    }
    __syncthreads();
    if (tid < 32) {
      float hv = ws[WS_B + (s + 1) * 32 + tid];
      const float* wrow = Wm + tid * 64;
      for (int d = 0; d < 64; ++d) hv = fmaf(-wrow[d], mnS[d], hv);
      hC[tid] = hv;
    }
    __syncthreads();
  };

  // ---- init: X0 with k_init; z = b0 - W X0; gumbel uk[0] ----
  genE(keyL[258], keyL[259]);
  genG(keyL[128], keyL[129]);
  genTail(Wm);
  bar_arrive();
  genE(keyL[0], keyL[1]);          // E for step 0 transition (nk[0])
  genG(keyL[128 + 2], keyL[128 + 3]);  // gumbel uk[1]
  bar_wait();

  for (int s = 0; s < 64; ++s) {
    combine(s);
    bar_arrive();
    bar_wait();
    meanH(s);
    genTail(Ms);
    bar_arrive();
    if (s < 63) {
      genE(keyL[2 * (s + 1)], keyL[2 * (s + 1) + 1]);
      genG(keyL[128 + 2 * (s + 2)], keyL[128 + 2 * (s + 2) + 1]);
    }
    bar_wait();
  }

  // ---- final: lml += logsumexp(lw_64); block0 writes ----
  if (tid < 256) redB[tid] = ws[WS_PMLW + tid];
  __syncthreads();
  for (int st = 128; st > 0; st >>= 1) {
    if (tid < st) redB[tid] = fmaxf(redB[tid], redB[tid + st]);
    __syncthreads();
  }
  const float mlwg = redB[0];
  __syncthreads();
  if (tid < 256) redB[tid] = expf(ws[WS_PMLW + tid] - mlwg) * ws[WS_PZLW + tid];
  __syncthreads();
  for (int st = 128; st > 0; st >>= 1) {
    if (tid < st) redB[tid] += redB[tid + st];
    __syncthreads();
  }
  if (tid == 0 && bid == 0) dout[0] = sc[4] + mlwg + logf(redB[0]);
}

extern "C" void kernel_launch(void* const* d_in, const int* in_sizes, int n_in,
                              void* d_out, int out_size, void* d_ws, size_t ws_size,
                              hipStream_t stream) {
  const float* obs = (const float*)d_in[0];
  const float* Am = (const float*)d_in[1];
  const float* Cm = (const float*)d_in[2];
  const float* Qt = (const float*)d_in[3];
  const float* Qc = (const float*)d_in[4];
  const float* Rc = (const float*)d_in[5];
  float* ws = (float*)d_ws;
  float* out = (float*)d_out;
  (void)in_sizes; (void)n_in; (void)out_size; (void)ws_size;

  kp_kernel<<<dim3(1), dim3(1024), 0, stream>>>(ws, obs, Cm, Qc, Rc);

  void* params[] = { (void*)&ws, (void*)&Am, (void*)&Qc, (void*)&Qt, (void*)&out };
  hipLaunchCooperativeKernel((const void*)kmain_kernel, dim3(256), dim3(512),
                             params, 0, stream);
}